// Round 19
// baseline (84.461 us; speedup 1.0000x reference)
//
#include <hip/hip_runtime.h>
#include <hip/hip_bf16.h>

// ProductLayer: B=4096, F=32, D=64, U=256
// out[:,   0:256] = lz       = E[B,2048] @ W1[2048,256]  (E consumed DIRECTLY from
//                              fp32 embeds in-kernel: reg-stage + cvt + swizzled ds_write)
// out[:, 256:512] = lp_inner = G[B,1024] @ V [1024,256]  (G = gram, materialized by prep)
// out[:, 512:768] = lp_outer = M[B,4096] @ W2[4096,256]  (M rank-1 from FST, in-register)
// A = G-only bf16 [4096, 1024]; FST bf16 [32][64][128]; Wt bf16 [256, 7168] (N-major)
// v19 = r18 with the E round-trip eliminated. seg1/seg2/prep_w/zero identical to r18.
// seg0: fp32 A-tile reg-staged (8 float4/thread/step, issued one step ahead),
// cvt_pk -> swizzled ds_write_b128; B still global_load_lds dbuf. 768 blocks, 48 KB LDS.

#define KG 1024
#define KW 7168

typedef __attribute__((ext_vector_type(8))) short short8v;
typedef __attribute__((ext_vector_type(4))) float f32x4;

#define GLOAD(src, dst) __builtin_amdgcn_global_load_lds( \
    (const __attribute__((address_space(1))) void*)(src), \
    (__attribute__((address_space(3))) void*)(dst), 16, 0, 0)

static __device__ __forceinline__ short f2bf(float f) {
    union { float f; unsigned u; } v; v.f = f;
    unsigned r = v.u + 0x7fffu + ((v.u >> 16) & 1u);  // RNE
    return (short)(r >> 16);
}
static __device__ __forceinline__ float bf2f(short s) {
    union { unsigned u; float f; } v; v.u = ((unsigned)(unsigned short)s) << 16;
    return v.f;
}
static __device__ __forceinline__ int cvtpk(float lo, float hi) {
    int r;
    asm("v_cvt_pk_bf16_f32 %0, %1, %2" : "=v"(r) : "v"(lo), "v"(hi));
    return r;
}

// ---- prep: [0,1024) prep_a 4 rows/block (G+FST only); [1024,1280) prep_w; [1280,2304) zero ----
__global__ __launch_bounds__(256) void prep(const float* __restrict__ embeds,
                                            const float* __restrict__ lw,
                                            const float* __restrict__ iw,
                                            const float* __restrict__ ow,
                                            short* __restrict__ A,
                                            short* __restrict__ FST,
                                            short* __restrict__ Wt,
                                            float4* __restrict__ outv) {
    __shared__ short sebf[4][2048];   // 16 KB, per-wave row
    __shared__ float sew[32];
    int t = threadIdx.x;

    if (blockIdx.x >= 1280) {
        // zero cols [512,768): 4096 rows x 64 float4
        int idx = (blockIdx.x - 1280) * 256 + t;
        int row = idx >> 6, c4 = idx & 63;
        outv[(size_t)row * 192 + 128 + c4] = (float4){0.f, 0.f, 0.f, 0.f};
        return;
    }

    if (blockIdx.x < 1024) {
        int row = t >> 6, lane = t & 63;
        int b = blockIdx.x * 4 + row;
        const float* e = embeds + (size_t)b * 2048;
        short* arow = A + (size_t)b * KG;

        float4 fa[4], fb[4];
        #pragma unroll
        for (int j = 0; j < 4; ++j) {
            fa[j] = ((const float4*)e)[2 * lane + j * 128];
            fb[j] = ((const float4*)e)[2 * lane + 1 + j * 128];
        }
        #pragma unroll
        for (int j = 0; j < 4; ++j) {
            short8v sb;
            sb[0] = f2bf(fa[j].x); sb[1] = f2bf(fa[j].y);
            sb[2] = f2bf(fa[j].z); sb[3] = f2bf(fa[j].w);
            sb[4] = f2bf(fb[j].x); sb[5] = f2bf(fb[j].y);
            sb[6] = f2bf(fb[j].z); sb[7] = f2bf(fb[j].w);
            *(short8v*)&sebf[row][8 * lane + j * 512] = sb;   // LDS only (no E store)
        }
        // fs in-register via shfl (see r18 derivation)
        float ps[8];
        #pragma unroll
        for (int j = 0; j < 4; ++j) {
            float v[8] = {fa[j].x, fa[j].y, fa[j].z, fa[j].w,
                          fb[j].x, fb[j].y, fb[j].z, fb[j].w};
            #pragma unroll
            for (int e2 = 0; e2 < 8; ++e2) ps[e2] = (j == 0) ? v[e2] : ps[e2] + v[e2];
        }
        #pragma unroll
        for (int m = 8; m <= 32; m <<= 1)
            #pragma unroll
            for (int e2 = 0; e2 < 8; ++e2) ps[e2] += __shfl_xor(ps[e2], m, 64);
        if (lane < 8) {
            #pragma unroll
            for (int e2 = 0; e2 < 8; ++e2) {
                int d = 8 * lane + e2;
                FST[((size_t)(b >> 7)) * 8192 + d * 128 + (b & 127)] = f2bf(ps[e2]);
            }
        }
        // G = E E^T for this wave's row: 4 tiles of 16x16
        int lr = lane & 15, lk = (lane >> 4) * 8;
        #pragma unroll
        for (int tm = 0; tm < 2; ++tm)
            #pragma unroll
            for (int tn = 0; tn < 2; ++tn) {
                f32x4 g = {0.f, 0.f, 0.f, 0.f};
                #pragma unroll
                for (int ks = 0; ks < 2; ++ks) {
                    short8v a  = *(const short8v*)&sebf[row][(tm * 16 + lr) * 64 + ks * 32 + lk];
                    short8v bb = *(const short8v*)&sebf[row][(tn * 16 + lr) * 64 + ks * 32 + lk];
                    g = __builtin_amdgcn_mfma_f32_16x16x32_bf16(a, bb, g, 0, 0, 0);
                }
                #pragma unroll
                for (int r = 0; r < 4; ++r) {
                    int grow = tm * 16 + (lane >> 4) * 4 + r;
                    int gcol = tn * 16 + lr;
                    arow[grow * 32 + gcol] = f2bf(g[r]);
                }
            }
    } else {
        int u = blockIdx.x - 1024;
        short* w = Wt + (size_t)u * KW;

        for (int k = t; k < 2048; k += 256) w[k] = f2bf(lw[(size_t)k * 256 + u]);

        if (t < 32) sew[t] = iw[u * 32 + t];
        __syncthreads();
        for (int idx = t; idx < 1024; idx += 256)
            w[2048 + idx] = f2bf(sew[idx >> 5] * sew[idx & 31]);

        const float* owu = ow + (size_t)u * 4096;
        for (int i = t; i < 512; i += 256) {
            float4 a = ((const float4*)owu)[i * 2];
            float4 b = ((const float4*)owu)[i * 2 + 1];
            short8v s;
            s[0] = f2bf(a.x); s[1] = f2bf(a.y); s[2] = f2bf(a.z); s[3] = f2bf(a.w);
            s[4] = f2bf(b.x); s[5] = f2bf(b.y); s[6] = f2bf(b.z); s[7] = f2bf(b.w);
            *(short8v*)&w[3072 + i * 8] = s;
        }
    }
}

// ---- GEMM v19: 768 blocks x 4 waves (32x64), BM=128 BN=64 BK=64 ----
// xcd = id&7, s = id>>3 (0..95):
//   s 0-15:  seg0 full-K (nk=32), A from fp32 embeds (reg-stage+cvt+ds_write), plain stores
//   s 16-31: seg1 full-K (nk=16), A = G via global_load_lds, plain stores
//   s 32-95: seg2 split-K4 (nk=16), M rank-1 from FST, atomics. mt = xcd*4 + mtl.
__global__ __launch_bounds__(256) void gemm_tile(const float* __restrict__ embeds,
                                                 const short* __restrict__ A,
                                                 const short* __restrict__ Wt,
                                                 const short* __restrict__ FST,
                                                 float* __restrict__ out) {
    __shared__ short As[2][8192];    // 16 KB each (seg2: As[0] = FST tile [64 i][128 row])
    __shared__ short Bs[2][4096];    // 8 KB each

    int id = blockIdx.x;
    int xcd = id & 7, s = id >> 3;
    int seg, mtl, nt, kc, nk;
    if (s < 16)      { seg = 0; mtl = s & 3;  nt = s >> 2;        kc = 0;       nk = 32; }
    else if (s < 32) { int q = s - 16; seg = 1; mtl = q & 3; nt = q >> 2;       kc = 0;  nk = 16; }
    else             { int q = s - 32; seg = 2; mtl = q & 3; nt = (q >> 2) & 3; kc = q >> 4; nk = 16; }
    int mt = xcd * 4 + mtl;
    int brow = mt * 128, bcol = nt * 64;
    int boff  = (seg == 0) ? 0 : (seg == 1) ? 2048 : 3072 + kc * 1024;

    int t = threadIdx.x, w = t >> 6, lane = t & 63;
    int lr = lane & 15, hi = lane >> 4;
    int srow = t >> 3;                       // staging row 0..31 per issue
    int soct = (t & 7) ^ (srow & 7);         // pre-swizzled source octet (involution)

    const short* Bsrc = Wt + (size_t)(bcol + srow) * KW + boff  + soct * 8;
    const short* Fsrc = FST + (size_t)mt * 8192;   // transposed tile, linear

    auto stageB = [&](int p, int kt) {
        #pragma unroll
        for (int i = 0; i < 2; ++i)
            GLOAD(Bsrc + (size_t)i * 32 * KW + kt * 64, &Bs[p][i * 2048 + t * 8]);
    };

    f32x4 acc[2][4];
    #pragma unroll
    for (int m = 0; m < 2; ++m)
        #pragma unroll
        for (int n = 0; n < 4; ++n) acc[m][n] = (f32x4){0.f, 0.f, 0.f, 0.f};

    auto compute = [&](const short* a_s, const short* b_s) {
        #pragma unroll
        for (int ks = 0; ks < 2; ++ks) {
            int oct = ((ks * 4 + hi) ^ (lr & 7)) * 8;   // swizzled read octet
            short8v a[2], b[4];
            #pragma unroll
            for (int m = 0; m < 2; ++m)
                a[m] = *(const short8v*)&a_s[(w * 32 + m * 16 + lr) * 64 + oct];
            #pragma unroll
            for (int n = 0; n < 4; ++n)
                b[n] = *(const short8v*)&b_s[(n * 16 + lr) * 64 + oct];
            __builtin_amdgcn_s_setprio(1);
            #pragma unroll
            for (int m = 0; m < 2; ++m)
                #pragma unroll
                for (int n = 0; n < 4; ++n)
                    acc[m][n] = __builtin_amdgcn_mfma_f32_16x16x32_bf16(a[m], b[n], acc[m][n], 0, 0, 0);
            __builtin_amdgcn_s_setprio(0);
        }
    };

    if (seg == 0) {
        // A staged from fp32 embeds: thread = (row r = t>>1, half h = t&1).
        int r = t >> 1, h = t & 1;
        const float4* Ef = (const float4*)embeds + (size_t)(brow + r) * 512 + h * 8;
        short* myA0 = &As[0][r * 64];    // logical octets 4h..4h+3, phys j^(r&7)
        short* myA1 = &As[1][r * 64];
        float4 ar[8];
        auto aload = [&](int kt) {
            #pragma unroll
            for (int i = 0; i < 8; ++i) ar[i] = Ef[kt * 16 + i];
        };
        auto awrite = [&](short* dst) {
            #pragma unroll
            for (int j2 = 0; j2 < 4; ++j2) {
                short8v sv;
                float4 x = ar[2 * j2], y = ar[2 * j2 + 1];
                union { int i32[4]; short8v v; } u2;
                u2.i32[0] = cvtpk(x.x, x.y); u2.i32[1] = cvtpk(x.z, x.w);
                u2.i32[2] = cvtpk(y.x, y.y); u2.i32[3] = cvtpk(y.z, y.w);
                sv = u2.v;
                *(short8v*)&dst[(((4 * h + j2) ^ (r & 7)) * 8)] = sv;
            }
        };

        aload(0);
        asm volatile("s_waitcnt vmcnt(0)" ::: "memory");
        awrite(myA0);
        stageB(0, 0); stageB(1, 1);          // 4 vm
        aload(1);                            // 8 vm
        asm volatile("s_waitcnt vmcnt(10) lgkmcnt(0)" ::: "memory");  // B(0)+my writes done
        __builtin_amdgcn_s_barrier();
        __builtin_amdgcn_sched_barrier(0);
        for (int kt = 0; kt < 32; ++kt) {
            int cur = kt & 1;
            compute(As[cur], Bs[cur]);
            __builtin_amdgcn_sched_barrier(0);
            __builtin_amdgcn_s_barrier();    // all waves done reading buf cur
            if (kt + 1 < 32) {
                asm volatile("s_waitcnt vmcnt(0)" ::: "memory");   // ar(kt+1) + B(kt+1) landed
                awrite(cur ? myA0 : myA1);                          // As[nxt]
                if (kt + 2 < 32) { stageB(cur, kt + 2); aload(kt + 2); }
                asm volatile("s_waitcnt lgkmcnt(0)" ::: "memory");
                __builtin_amdgcn_s_barrier();
                __builtin_amdgcn_sched_barrier(0);
            }
        }
    } else if (seg == 1) {
        const short* Asrc = A + (size_t)(brow + srow) * KG + soct * 8;
        auto stageA = [&](int p, int kt) {
            #pragma unroll
            for (int i = 0; i < 4; ++i)
                GLOAD(Asrc + (size_t)i * 32 * KG + kt * 64, &As[p][i * 2048 + t * 8]);
        };
        stageA(0, 0); stageB(0, 0);
        stageA(1, 1); stageB(1, 1);            // 12 vm-ops in flight
        __builtin_amdgcn_sched_barrier(0);
        for (int kt = 0; kt < 16; ++kt) {
            int cur = kt & 1;
            if (kt + 1 < 16) asm volatile("s_waitcnt vmcnt(6)" ::: "memory");
            else             asm volatile("s_waitcnt vmcnt(0)" ::: "memory");
            __builtin_amdgcn_s_barrier();
            __builtin_amdgcn_sched_barrier(0);
            compute(As[cur], Bs[cur]);
            __builtin_amdgcn_sched_barrier(0);
            __builtin_amdgcn_s_barrier();
            if (kt + 2 < 16) { stageA(cur, kt + 2); stageB(cur, kt + 2); }
            __builtin_amdgcn_sched_barrier(0);
        }
    } else {
        #pragma unroll
        for (int i = 0; i < 4; ++i)              // FST tile [64 i][128 row] -> As[0], linear
            GLOAD(Fsrc + i * 2048 + t * 8, &As[0][i * 2048 + t * 8]);
        stageB(0, 0); stageB(1, 1);              // 4 + 4 vm-ops in flight
        asm volatile("s_waitcnt vmcnt(4)" ::: "memory");   // FST landed
        __builtin_amdgcn_s_barrier();
        __builtin_amdgcn_sched_barrier(0);

        float fj[2][2][8];
        #pragma unroll
        for (int m = 0; m < 2; ++m) {
            int row = w * 32 + m * 16 + lr;
            #pragma unroll
            for (int ks = 0; ks < 2; ++ks) {
                int j0 = (ks * 4 + hi) * 8;
                #pragma unroll
                for (int e = 0; e < 8; ++e)
                    fj[m][ks][e] = bf2f(As[0][(j0 + e) * 128 + row]);
            }
        }
        for (int kt = 0; kt < 16; ++kt) {
            int cur = kt & 1;
            if (kt + 1 < 16) asm volatile("s_waitcnt vmcnt(2)" ::: "memory");
            else             asm volatile("s_waitcnt vmcnt(0)" ::: "memory");
            __builtin_amdgcn_s_barrier();
            __builtin_amdgcn_sched_barrier(0);
            int iidx = kc * 16 + kt;             // rank-1 column index 0..63
            float sv[2];
            #pragma unroll
            for (int m = 0; m < 2; ++m)
                sv[m] = bf2f(As[0][iidx * 128 + w * 32 + m * 16 + lr]);
            #pragma unroll
            for (int ks = 0; ks < 2; ++ks) {
                int oct = ((ks * 4 + hi) ^ (lr & 7)) * 8;
                short8v b[4];
                #pragma unroll
                for (int n = 0; n < 4; ++n)
                    b[n] = *(const short8v*)&Bs[cur][(n * 16 + lr) * 64 + oct];
                #pragma unroll
                for (int m = 0; m < 2; ++m) {
                    union { int i32[4]; short8v v; } fa;
                    #pragma unroll
                    for (int q2 = 0; q2 < 4; ++q2)
                        fa.i32[q2] = cvtpk(sv[m] * fj[m][ks][2 * q2], sv[m] * fj[m][ks][2 * q2 + 1]);
                    __builtin_amdgcn_s_setprio(1);
                    #pragma unroll
                    for (int n = 0; n < 4; ++n)
                        acc[m][n] = __builtin_amdgcn_mfma_f32_16x16x32_bf16(fa.v, b[n], acc[m][n], 0, 0, 0);
                    __builtin_amdgcn_s_setprio(0);
                }
            }
            __builtin_amdgcn_sched_barrier(0);
            __builtin_amdgcn_s_barrier();
            if (kt + 2 < 16) stageB(cur, kt + 2);
            __builtin_amdgcn_sched_barrier(0);
        }
    }

    int segbase = seg * 256;
    if (seg != 2) {
        #pragma unroll
        for (int m = 0; m < 2; ++m) {
            int row0 = brow + w * 32 + m * 16 + hi * 4;
            #pragma unroll
            for (int n = 0; n < 4; ++n) {
                int col = segbase + bcol + n * 16 + lr;
                #pragma unroll
                for (int r2 = 0; r2 < 4; ++r2)
                    out[(size_t)(row0 + r2) * 768 + col] = acc[m][n][r2];
            }
        }
    } else {
        #pragma unroll
        for (int m = 0; m < 2; ++m) {
            int row0 = brow + w * 32 + m * 16 + hi * 4;
            #pragma unroll
            for (int n = 0; n < 4; ++n) {
                int col = segbase + bcol + n * 16 + lr;
                #pragma unroll
                for (int r2 = 0; r2 < 4; ++r2)
                    unsafeAtomicAdd(&out[(size_t)(row0 + r2) * 768 + col], acc[m][n][r2]);
            }
        }
    }
}

extern "C" void kernel_launch(void* const* d_in, const int* in_sizes, int n_in,
                              void* d_out, int out_size, void* d_ws, size_t ws_size,
                              hipStream_t stream) {
    const float* embeds = (const float*)d_in[0];
    const float* lw = (const float*)d_in[1];
    const float* iw = (const float*)d_in[2];
    const float* ow = (const float*)d_in[3];
    float* out = (float*)d_out;

    short* A   = (short*)d_ws;                    // 4096*1024*2 = 8,388,608 B (G only)
    short* Wt  = A + (size_t)4096 * KG;           // + 256*7168*2 = 3,670,016 B
    short* FST = Wt + (size_t)256 * KW;           // + 32*64*128*2 =   524,288 B

    prep<<<dim3(2304), dim3(256), 0, stream>>>(embeds, lw, iw, ow, A, FST, Wt, (float4*)out);
    gemm_tile<<<dim3(768), dim3(256), 0, stream>>>(embeds, A, Wt, FST, out);
}

// Round 20
// 55.859 us; speedup vs baseline: 1.5120x; 1.5120x over previous
//
#include <hip/hip_runtime.h>
#include <hip/hip_bf16.h>

// ProductLayer: B=4096, F=32, D=64, U=256
// out[:,   0:256] = lz       = E[B,2048] @ W1[2048,256]
// out[:, 256:512] = lp_inner = G[B,1024] @ V [1024,256]   (G_b = E_b E_b^T gram)
// out[:, 512:768] = lp_outer = M[B,4096] @ W2[4096,256]   (M rank-1 from FST, in-register)
// A = [E | G] bf16 [4096, 3072]; FST bf16 [32][64][128]; Wt bf16 [256, 7168] (N-major)
// v20 = r18 verbatim (measured best, 55.2 us). gemm: seg0/seg1 full-K plain-store,
// seg2 split-K4 atomic, 768 blocks = 3/CU, 48 KB LDS, swizzle, depth-2 counted
// vmcnt, setprio. prep: 4 rows/block barrier-free (fs via shfl_xor, G via MFMA).

#define KA 3072
#define KW 7168

typedef __attribute__((ext_vector_type(8))) short short8v;
typedef __attribute__((ext_vector_type(4))) float f32x4;

#define GLOAD(src, dst) __builtin_amdgcn_global_load_lds( \
    (const __attribute__((address_space(1))) void*)(src), \
    (__attribute__((address_space(3))) void*)(dst), 16, 0, 0)

static __device__ __forceinline__ short f2bf(float f) {
    union { float f; unsigned u; } v; v.f = f;
    unsigned r = v.u + 0x7fffu + ((v.u >> 16) & 1u);  // RNE
    return (short)(r >> 16);
}
static __device__ __forceinline__ float bf2f(short s) {
    union { unsigned u; float f; } v; v.u = ((unsigned)(unsigned short)s) << 16;
    return v.f;
}
static __device__ __forceinline__ int cvtpk(float lo, float hi) {
    int r;
    asm("v_cvt_pk_bf16_f32 %0, %1, %2" : "=v"(r) : "v"(lo), "v"(hi));
    return r;
}

// ---- prep: blocks [0,1024) prep_a 4 rows each; [1024,1280) prep_w; [1280,2304) zero ----
__global__ __launch_bounds__(256) void prep(const float* __restrict__ embeds,
                                            const float* __restrict__ lw,
                                            const float* __restrict__ iw,
                                            const float* __restrict__ ow,
                                            short* __restrict__ A,
                                            short* __restrict__ FST,
                                            short* __restrict__ Wt,
                                            float4* __restrict__ outv) {
    __shared__ short sebf[4][2048];   // 16 KB, per-wave row
    __shared__ float sew[32];
    int t = threadIdx.x;

    if (blockIdx.x >= 1280) {
        // zero cols [512,768): 4096 rows x 64 float4
        int idx = (blockIdx.x - 1280) * 256 + t;
        int row = idx >> 6, c4 = idx & 63;
        outv[(size_t)row * 192 + 128 + c4] = (float4){0.f, 0.f, 0.f, 0.f};
        return;
    }

    if (blockIdx.x < 1024) {
        int row = t >> 6, lane = t & 63;
        int b = blockIdx.x * 4 + row;
        const float* e = embeds + (size_t)b * 2048;
        short* arow = A + (size_t)b * KA;

        // load 32 floats: groups j=0..3, floats [8*lane + j*512, +8)
        float4 fa[4], fb[4];
        #pragma unroll
        for (int j = 0; j < 4; ++j) {
            fa[j] = ((const float4*)e)[2 * lane + j * 128];
            fb[j] = ((const float4*)e)[2 * lane + 1 + j * 128];
        }
        // E cast + store (global + LDS)
        #pragma unroll
        for (int j = 0; j < 4; ++j) {
            short8v sb;
            sb[0] = f2bf(fa[j].x); sb[1] = f2bf(fa[j].y);
            sb[2] = f2bf(fa[j].z); sb[3] = f2bf(fa[j].w);
            sb[4] = f2bf(fb[j].x); sb[5] = f2bf(fb[j].y);
            sb[6] = f2bf(fb[j].z); sb[7] = f2bf(fb[j].w);
            *(short8v*)&arow[8 * lane + j * 512] = sb;
            *(short8v*)&sebf[row][8 * lane + j * 512] = sb;
        }
        // fs in-register: float index p = 8*lane + e + j*512; d = (8*lane+e)&63;
        // f = ((8*lane+e)>>6) + 8*j. partial[e] sums j; lanes {^8,^16,^32} complete.
        float ps[8];
        #pragma unroll
        for (int j = 0; j < 4; ++j) {
            float v[8] = {fa[j].x, fa[j].y, fa[j].z, fa[j].w,
                          fb[j].x, fb[j].y, fb[j].z, fb[j].w};
            #pragma unroll
            for (int e2 = 0; e2 < 8; ++e2) ps[e2] = (j == 0) ? v[e2] : ps[e2] + v[e2];
        }
        #pragma unroll
        for (int m = 8; m <= 32; m <<= 1)
            #pragma unroll
            for (int e2 = 0; e2 < 8; ++e2) ps[e2] += __shfl_xor(ps[e2], m, 64);
        if (lane < 8) {
            #pragma unroll
            for (int e2 = 0; e2 < 8; ++e2) {
                int d = 8 * lane + e2;   // fs index
                FST[((size_t)(b >> 7)) * 8192 + d * 128 + (b & 127)] = f2bf(ps[e2]);
            }
        }

        // G = E E^T for this wave's row: 4 tiles of 16x16, K=64 in 2 MFMA each.
        int lr = lane & 15, lk = (lane >> 4) * 8;
        #pragma unroll
        for (int tm = 0; tm < 2; ++tm)
            #pragma unroll
            for (int tn = 0; tn < 2; ++tn) {
                f32x4 g = {0.f, 0.f, 0.f, 0.f};
                #pragma unroll
                for (int ks = 0; ks < 2; ++ks) {
                    short8v a  = *(const short8v*)&sebf[row][(tm * 16 + lr) * 64 + ks * 32 + lk];
                    short8v bb = *(const short8v*)&sebf[row][(tn * 16 + lr) * 64 + ks * 32 + lk];
                    g = __builtin_amdgcn_mfma_f32_16x16x32_bf16(a, bb, g, 0, 0, 0);
                }
                #pragma unroll
                for (int r = 0; r < 4; ++r) {
                    int grow = tm * 16 + (lane >> 4) * 4 + r;
                    int gcol = tn * 16 + lr;
                    arow[2048 + grow * 32 + gcol] = f2bf(g[r]);  // G segment [2048, 3072)
                }
            }
    } else {
        int u = blockIdx.x - 1024;
        short* w = Wt + (size_t)u * KW;

        for (int k = t; k < 2048; k += 256) w[k] = f2bf(lw[(size_t)k * 256 + u]);

        if (t < 32) sew[t] = iw[u * 32 + t];
        __syncthreads();
        for (int idx = t; idx < 1024; idx += 256)
            w[2048 + idx] = f2bf(sew[idx >> 5] * sew[idx & 31]);

        const float* owu = ow + (size_t)u * 4096;
        for (int i = t; i < 512; i += 256) {
            float4 a = ((const float4*)owu)[i * 2];
            float4 b = ((const float4*)owu)[i * 2 + 1];
            short8v s;
            s[0] = f2bf(a.x); s[1] = f2bf(a.y); s[2] = f2bf(a.z); s[3] = f2bf(a.w);
            s[4] = f2bf(b.x); s[5] = f2bf(b.y); s[6] = f2bf(b.z); s[7] = f2bf(b.w);
            *(short8v*)&w[3072 + i * 8] = s;
        }
    }
}

// ---- GEMM (r16 structure): 768 blocks x 4 waves (32x64), BM=128 BN=64 BK=64 ----
// xcd = id&7, s = id>>3 (0..95):
//   s 0-15:  seg0 full-K (nk=32), plain stores; s 16-31: seg1 full-K (nk=16), plain;
//   s 32-95: seg2 split-K4 (nk=16), atomic. mt = xcd*4 + mtl.
__global__ __launch_bounds__(256) void gemm_tile(const short* __restrict__ A,
                                                 const short* __restrict__ Wt,
                                                 const short* __restrict__ FST,
                                                 float* __restrict__ out) {
    __shared__ short As[2][8192];    // 16 KB each (seg2: As[0] = FST tile [64 i][128 row])
    __shared__ short Bs[2][4096];    // 8 KB each

    int id = blockIdx.x;
    int xcd = id & 7, s = id >> 3;
    int seg, mtl, nt, kc, nk;
    if (s < 16)      { seg = 0; mtl = s & 3;  nt = s >> 2;        kc = 0;       nk = 32; }
    else if (s < 32) { int q = s - 16; seg = 1; mtl = q & 3; nt = q >> 2;       kc = 0;  nk = 16; }
    else             { int q = s - 32; seg = 2; mtl = q & 3; nt = (q >> 2) & 3; kc = q >> 4; nk = 16; }
    int mt = xcd * 4 + mtl;
    int brow = mt * 128, bcol = nt * 64;
    int akoff = (seg == 0) ? 0 : 2048;
    int boff  = (seg == 0) ? 0 : (seg == 1) ? 2048 : 3072 + kc * 1024;

    int t = threadIdx.x, w = t >> 6, lane = t & 63;
    int lr = lane & 15, hi = lane >> 4;
    int srow = t >> 3;                       // staging row 0..31 per issue
    int soct = (t & 7) ^ (srow & 7);         // pre-swizzled source octet (involution)

    const short* Asrc = A  + (size_t)(brow + srow) * KA + akoff + soct * 8;
    const short* Bsrc = Wt + (size_t)(bcol + srow) * KW + boff  + soct * 8;
    const short* Fsrc = FST + (size_t)mt * 8192;   // transposed tile, linear

    auto stageA = [&](int p, int kt) {
        #pragma unroll
        for (int i = 0; i < 4; ++i)
            GLOAD(Asrc + (size_t)i * 32 * KA + kt * 64, &As[p][i * 2048 + t * 8]);
    };
    auto stageB = [&](int p, int kt) {
        #pragma unroll
        for (int i = 0; i < 2; ++i)
            GLOAD(Bsrc + (size_t)i * 32 * KW + kt * 64, &Bs[p][i * 2048 + t * 8]);
    };

    f32x4 acc[2][4];
    #pragma unroll
    for (int m = 0; m < 2; ++m)
        #pragma unroll
        for (int n = 0; n < 4; ++n) acc[m][n] = (f32x4){0.f, 0.f, 0.f, 0.f};

    auto compute = [&](const short* a_s, const short* b_s) {
        #pragma unroll
        for (int ks = 0; ks < 2; ++ks) {
            int oct = ((ks * 4 + hi) ^ (lr & 7)) * 8;   // swizzled read octet
            short8v a[2], b[4];
            #pragma unroll
            for (int m = 0; m < 2; ++m)
                a[m] = *(const short8v*)&a_s[(w * 32 + m * 16 + lr) * 64 + oct];
            #pragma unroll
            for (int n = 0; n < 4; ++n)
                b[n] = *(const short8v*)&b_s[(n * 16 + lr) * 64 + oct];
            __builtin_amdgcn_s_setprio(1);
            #pragma unroll
            for (int m = 0; m < 2; ++m)
                #pragma unroll
                for (int n = 0; n < 4; ++n)
                    acc[m][n] = __builtin_amdgcn_mfma_f32_16x16x32_bf16(a[m], b[n], acc[m][n], 0, 0, 0);
            __builtin_amdgcn_s_setprio(0);
        }
    };

    if (seg != 2) {
        stageA(0, 0); stageB(0, 0);
        stageA(1, 1); stageB(1, 1);            // 12 vm-ops in flight
        __builtin_amdgcn_sched_barrier(0);
        for (int kt = 0; kt < nk; ++kt) {
            int cur = kt & 1;
            if (kt + 1 < nk) asm volatile("s_waitcnt vmcnt(6)" ::: "memory");
            else             asm volatile("s_waitcnt vmcnt(0)" ::: "memory");
            __builtin_amdgcn_s_barrier();          // all waves' stage-kt landed
            __builtin_amdgcn_sched_barrier(0);
            compute(As[cur], Bs[cur]);
            __builtin_amdgcn_sched_barrier(0);
            __builtin_amdgcn_s_barrier();          // all waves done reading buf cur
            if (kt + 2 < nk) { stageA(cur, kt + 2); stageB(cur, kt + 2); }
            __builtin_amdgcn_sched_barrier(0);
        }
    } else {
        #pragma unroll
        for (int i = 0; i < 4; ++i)              // FST tile [64 i][128 row] -> As[0], linear
            GLOAD(Fsrc + i * 2048 + t * 8, &As[0][i * 2048 + t * 8]);
        stageB(0, 0); stageB(1, 1);              // 4 + 4 vm-ops in flight
        asm volatile("s_waitcnt vmcnt(4)" ::: "memory");   // FST landed
        __builtin_amdgcn_s_barrier();
        __builtin_amdgcn_sched_barrier(0);

        // fj[m][ks][e] = fs[row_m][(ks*4+hi)*8+e] from transposed tile (conflict-free)
        float fj[2][2][8];
        #pragma unroll
        for (int m = 0; m < 2; ++m) {
            int row = w * 32 + m * 16 + lr;
            #pragma unroll
            for (int ks = 0; ks < 2; ++ks) {
                int j0 = (ks * 4 + hi) * 8;
                #pragma unroll
                for (int e = 0; e < 8; ++e)
                    fj[m][ks][e] = bf2f(As[0][(j0 + e) * 128 + row]);
            }
        }
        for (int kt = 0; kt < nk; ++kt) {
            int cur = kt & 1;
            if (kt + 1 < nk) asm volatile("s_waitcnt vmcnt(2)" ::: "memory");
            else             asm volatile("s_waitcnt vmcnt(0)" ::: "memory");
            __builtin_amdgcn_s_barrier();
            __builtin_amdgcn_sched_barrier(0);
            int iidx = kc * 16 + kt;             // rank-1 column index 0..63
            float sv[2];
            #pragma unroll
            for (int m = 0; m < 2; ++m)
                sv[m] = bf2f(As[0][iidx * 128 + w * 32 + m * 16 + lr]);
            #pragma unroll
            for (int ks = 0; ks < 2; ++ks) {
                int oct = ((ks * 4 + hi) ^ (lr & 7)) * 8;
                short8v b[4];
                #pragma unroll
                for (int n = 0; n < 4; ++n)
                    b[n] = *(const short8v*)&Bs[cur][(n * 16 + lr) * 64 + oct];
                #pragma unroll
                for (int m = 0; m < 2; ++m) {
                    union { int i32[4]; short8v v; } fa;
                    #pragma unroll
                    for (int q2 = 0; q2 < 4; ++q2)
                        fa.i32[q2] = cvtpk(sv[m] * fj[m][ks][2 * q2], sv[m] * fj[m][ks][2 * q2 + 1]);
                    __builtin_amdgcn_s_setprio(1);
                    #pragma unroll
                    for (int n = 0; n < 4; ++n)
                        acc[m][n] = __builtin_amdgcn_mfma_f32_16x16x32_bf16(fa.v, b[n], acc[m][n], 0, 0, 0);
                    __builtin_amdgcn_s_setprio(0);
                }
            }
            __builtin_amdgcn_sched_barrier(0);
            __builtin_amdgcn_s_barrier();          // all waves done with Bs[cur]
            if (kt + 2 < nk) stageB(cur, kt + 2);
            __builtin_amdgcn_sched_barrier(0);
        }
    }

    int segbase = seg * 256;
    if (seg != 2) {
        #pragma unroll
        for (int m = 0; m < 2; ++m) {
            int row0 = brow + w * 32 + m * 16 + hi * 4;
            #pragma unroll
            for (int n = 0; n < 4; ++n) {
                int col = segbase + bcol + n * 16 + lr;
                #pragma unroll
                for (int r = 0; r < 4; ++r)
                    out[(size_t)(row0 + r) * 768 + col] = acc[m][n][r];
            }
        }
    } else {
        #pragma unroll
        for (int m = 0; m < 2; ++m) {
            int row0 = brow + w * 32 + m * 16 + hi * 4;
            #pragma unroll
            for (int n = 0; n < 4; ++n) {
                int col = segbase + bcol + n * 16 + lr;
                #pragma unroll
                for (int r = 0; r < 4; ++r)
                    unsafeAtomicAdd(&out[(size_t)(row0 + r) * 768 + col], acc[m][n][r]);
            }
        }
    }
}

extern "C" void kernel_launch(void* const* d_in, const int* in_sizes, int n_in,
                              void* d_out, int out_size, void* d_ws, size_t ws_size,
                              hipStream_t stream) {
    const float* embeds = (const float*)d_in[0];
    const float* lw = (const float*)d_in[1];
    const float* iw = (const float*)d_in[2];
    const float* ow = (const float*)d_in[3];
    float* out = (float*)d_out;

    short* A   = (short*)d_ws;                    // 4096*3072*2 = 25,165,824 B
    short* Wt  = A + (size_t)4096 * KA;           // + 256*7168*2 = 3,670,016 B
    short* FST = Wt + (size_t)256 * KW;           // + 32*64*128*2 =   524,288 B

    prep<<<dim3(2304), dim3(256), 0, stream>>>(embeds, lw, iw, ow, A, FST, Wt, (float4*)out);
    gemm_tile<<<dim3(768), dim3(256), 0, stream>>>(A, Wt, FST, out);
}

// Round 21
// 54.676 us; speedup vs baseline: 1.5448x; 1.0216x over previous
//
#include <hip/hip_runtime.h>
#include <hip/hip_bf16.h>

// ProductLayer: B=4096, F=32, D=64, U=256
// out[:,   0:256] = lz       = E[B,2048] @ W1[2048,256]
// out[:, 256:512] = lp_inner = G[B,1024] @ V [1024,256]   (G_b = E_b E_b^T gram)
// out[:, 512:768] = lp_outer = M[B,4096] @ W2[4096,256]   (M rank-1 from FST, in-register)
// A = [E | G] bf16 [4096, 3072]; FST bf16 [32][64][128]; Wt bf16 [256, 7168] (N-major)
// v21 = r18/r20 (measured best 55.2/55.9 us) + seg2 4-deep B-prefetch: As[1]
// (unused in seg2) becomes 2 extra B buffers -> 2 K-steps per barrier-pair
// (barriers 33->17, 32 MFMA/phase). seg0/seg1/prep/epilogues unchanged.

#define KA 3072
#define KW 7168

typedef __attribute__((ext_vector_type(8))) short short8v;
typedef __attribute__((ext_vector_type(4))) float f32x4;

#define GLOAD(src, dst) __builtin_amdgcn_global_load_lds( \
    (const __attribute__((address_space(1))) void*)(src), \
    (__attribute__((address_space(3))) void*)(dst), 16, 0, 0)

static __device__ __forceinline__ short f2bf(float f) {
    union { float f; unsigned u; } v; v.f = f;
    unsigned r = v.u + 0x7fffu + ((v.u >> 16) & 1u);  // RNE
    return (short)(r >> 16);
}
static __device__ __forceinline__ float bf2f(short s) {
    union { unsigned u; float f; } v; v.u = ((unsigned)(unsigned short)s) << 16;
    return v.f;
}
static __device__ __forceinline__ int cvtpk(float lo, float hi) {
    int r;
    asm("v_cvt_pk_bf16_f32 %0, %1, %2" : "=v"(r) : "v"(lo), "v"(hi));
    return r;
}

// ---- prep: blocks [0,1024) prep_a 4 rows each; [1024,1280) prep_w; [1280,2304) zero ----
__global__ __launch_bounds__(256) void prep(const float* __restrict__ embeds,
                                            const float* __restrict__ lw,
                                            const float* __restrict__ iw,
                                            const float* __restrict__ ow,
                                            short* __restrict__ A,
                                            short* __restrict__ FST,
                                            short* __restrict__ Wt,
                                            float4* __restrict__ outv) {
    __shared__ short sebf[4][2048];   // 16 KB, per-wave row
    __shared__ float sew[32];
    int t = threadIdx.x;

    if (blockIdx.x >= 1280) {
        // zero cols [512,768): 4096 rows x 64 float4
        int idx = (blockIdx.x - 1280) * 256 + t;
        int row = idx >> 6, c4 = idx & 63;
        outv[(size_t)row * 192 + 128 + c4] = (float4){0.f, 0.f, 0.f, 0.f};
        return;
    }

    if (blockIdx.x < 1024) {
        int row = t >> 6, lane = t & 63;
        int b = blockIdx.x * 4 + row;
        const float* e = embeds + (size_t)b * 2048;
        short* arow = A + (size_t)b * KA;

        // load 32 floats: groups j=0..3, floats [8*lane + j*512, +8)
        float4 fa[4], fb[4];
        #pragma unroll
        for (int j = 0; j < 4; ++j) {
            fa[j] = ((const float4*)e)[2 * lane + j * 128];
            fb[j] = ((const float4*)e)[2 * lane + 1 + j * 128];
        }
        // E cast + store (global + LDS)
        #pragma unroll
        for (int j = 0; j < 4; ++j) {
            short8v sb;
            sb[0] = f2bf(fa[j].x); sb[1] = f2bf(fa[j].y);
            sb[2] = f2bf(fa[j].z); sb[3] = f2bf(fa[j].w);
            sb[4] = f2bf(fb[j].x); sb[5] = f2bf(fb[j].y);
            sb[6] = f2bf(fb[j].z); sb[7] = f2bf(fb[j].w);
            *(short8v*)&arow[8 * lane + j * 512] = sb;
            *(short8v*)&sebf[row][8 * lane + j * 512] = sb;
        }
        // fs in-register: partial sums over j, then lanes {^8,^16,^32} complete.
        float ps[8];
        #pragma unroll
        for (int j = 0; j < 4; ++j) {
            float v[8] = {fa[j].x, fa[j].y, fa[j].z, fa[j].w,
                          fb[j].x, fb[j].y, fb[j].z, fb[j].w};
            #pragma unroll
            for (int e2 = 0; e2 < 8; ++e2) ps[e2] = (j == 0) ? v[e2] : ps[e2] + v[e2];
        }
        #pragma unroll
        for (int m = 8; m <= 32; m <<= 1)
            #pragma unroll
            for (int e2 = 0; e2 < 8; ++e2) ps[e2] += __shfl_xor(ps[e2], m, 64);
        if (lane < 8) {
            #pragma unroll
            for (int e2 = 0; e2 < 8; ++e2) {
                int d = 8 * lane + e2;   // fs index
                FST[((size_t)(b >> 7)) * 8192 + d * 128 + (b & 127)] = f2bf(ps[e2]);
            }
        }

        // G = E E^T for this wave's row: 4 tiles of 16x16, K=64 in 2 MFMA each.
        int lr = lane & 15, lk = (lane >> 4) * 8;
        #pragma unroll
        for (int tm = 0; tm < 2; ++tm)
            #pragma unroll
            for (int tn = 0; tn < 2; ++tn) {
                f32x4 g = {0.f, 0.f, 0.f, 0.f};
                #pragma unroll
                for (int ks = 0; ks < 2; ++ks) {
                    short8v a  = *(const short8v*)&sebf[row][(tm * 16 + lr) * 64 + ks * 32 + lk];
                    short8v bb = *(const short8v*)&sebf[row][(tn * 16 + lr) * 64 + ks * 32 + lk];
                    g = __builtin_amdgcn_mfma_f32_16x16x32_bf16(a, bb, g, 0, 0, 0);
                }
                #pragma unroll
                for (int r = 0; r < 4; ++r) {
                    int grow = tm * 16 + (lane >> 4) * 4 + r;
                    int gcol = tn * 16 + lr;
                    arow[2048 + grow * 32 + gcol] = f2bf(g[r]);  // G segment [2048, 3072)
                }
            }
    } else {
        int u = blockIdx.x - 1024;
        short* w = Wt + (size_t)u * KW;

        for (int k = t; k < 2048; k += 256) w[k] = f2bf(lw[(size_t)k * 256 + u]);

        if (t < 32) sew[t] = iw[u * 32 + t];
        __syncthreads();
        for (int idx = t; idx < 1024; idx += 256)
            w[2048 + idx] = f2bf(sew[idx >> 5] * sew[idx & 31]);

        const float* owu = ow + (size_t)u * 4096;
        for (int i = t; i < 512; i += 256) {
            float4 a = ((const float4*)owu)[i * 2];
            float4 b = ((const float4*)owu)[i * 2 + 1];
            short8v s;
            s[0] = f2bf(a.x); s[1] = f2bf(a.y); s[2] = f2bf(a.z); s[3] = f2bf(a.w);
            s[4] = f2bf(b.x); s[5] = f2bf(b.y); s[6] = f2bf(b.z); s[7] = f2bf(b.w);
            *(short8v*)&w[3072 + i * 8] = s;
        }
    }
}

// ---- GEMM: 768 blocks x 4 waves (32x64), BM=128 BN=64 BK=64 ----
// xcd = id&7, s = id>>3 (0..95):
//   s 0-15:  seg0 full-K (nk=32), plain stores; s 16-31: seg1 full-K (nk=16), plain;
//   s 32-95: seg2 split-K4 (16 steps in 8 two-step phases), atomic. mt = xcd*4 + mtl.
__global__ __launch_bounds__(256) void gemm_tile(const short* __restrict__ A,
                                                 const short* __restrict__ Wt,
                                                 const short* __restrict__ FST,
                                                 float* __restrict__ out) {
    __shared__ short As[2][8192];    // 32 KB (seg2: As[0] = FST tile; As[1] = B bufs 2,3)
    __shared__ short Bs[2][4096];    // 16 KB

    int id = blockIdx.x;
    int xcd = id & 7, s = id >> 3;
    int seg, mtl, nt, kc, nk;
    if (s < 16)      { seg = 0; mtl = s & 3;  nt = s >> 2;        kc = 0;       nk = 32; }
    else if (s < 32) { int q = s - 16; seg = 1; mtl = q & 3; nt = q >> 2;       kc = 0;  nk = 16; }
    else             { int q = s - 32; seg = 2; mtl = q & 3; nt = (q >> 2) & 3; kc = q >> 4; nk = 16; }
    int mt = xcd * 4 + mtl;
    int brow = mt * 128, bcol = nt * 64;
    int akoff = (seg == 0) ? 0 : 2048;
    int boff  = (seg == 0) ? 0 : (seg == 1) ? 2048 : 3072 + kc * 1024;

    int t = threadIdx.x, w = t >> 6, lane = t & 63;
    int lr = lane & 15, hi = lane >> 4;
    int srow = t >> 3;                       // staging row 0..31 per issue
    int soct = (t & 7) ^ (srow & 7);         // pre-swizzled source octet (involution)

    const short* Asrc = A  + (size_t)(brow + srow) * KA + akoff + soct * 8;
    const short* Bsrc = Wt + (size_t)(bcol + srow) * KW + boff  + soct * 8;
    const short* Fsrc = FST + (size_t)mt * 8192;   // transposed tile, linear

    auto stageA = [&](int p, int kt) {
        #pragma unroll
        for (int i = 0; i < 4; ++i)
            GLOAD(Asrc + (size_t)i * 32 * KA + kt * 64, &As[p][i * 2048 + t * 8]);
    };
    auto stageB = [&](int p, int kt) {
        #pragma unroll
        for (int i = 0; i < 2; ++i)
            GLOAD(Bsrc + (size_t)i * 32 * KW + kt * 64, &Bs[p][i * 2048 + t * 8]);
    };
    auto stageB2 = [&](short* dst, int kt) {   // seg2: stage into arbitrary 8 KB buffer
        #pragma unroll
        for (int i = 0; i < 2; ++i)
            GLOAD(Bsrc + (size_t)i * 32 * KW + kt * 64, dst + i * 2048 + t * 8);
    };

    f32x4 acc[2][4];
    #pragma unroll
    for (int m = 0; m < 2; ++m)
        #pragma unroll
        for (int n = 0; n < 4; ++n) acc[m][n] = (f32x4){0.f, 0.f, 0.f, 0.f};

    auto compute = [&](const short* a_s, const short* b_s) {
        #pragma unroll
        for (int ks = 0; ks < 2; ++ks) {
            int oct = ((ks * 4 + hi) ^ (lr & 7)) * 8;   // swizzled read octet
            short8v a[2], b[4];
            #pragma unroll
            for (int m = 0; m < 2; ++m)
                a[m] = *(const short8v*)&a_s[(w * 32 + m * 16 + lr) * 64 + oct];
            #pragma unroll
            for (int n = 0; n < 4; ++n)
                b[n] = *(const short8v*)&b_s[(n * 16 + lr) * 64 + oct];
            __builtin_amdgcn_s_setprio(1);
            #pragma unroll
            for (int m = 0; m < 2; ++m)
                #pragma unroll
                for (int n = 0; n < 4; ++n)
                    acc[m][n] = __builtin_amdgcn_mfma_f32_16x16x32_bf16(a[m], b[n], acc[m][n], 0, 0, 0);
            __builtin_amdgcn_s_setprio(0);
        }
    };

    if (seg != 2) {
        stageA(0, 0); stageB(0, 0);
        stageA(1, 1); stageB(1, 1);            // 12 vm-ops in flight
        __builtin_amdgcn_sched_barrier(0);
        for (int kt = 0; kt < nk; ++kt) {
            int cur = kt & 1;
            if (kt + 1 < nk) asm volatile("s_waitcnt vmcnt(6)" ::: "memory");
            else             asm volatile("s_waitcnt vmcnt(0)" ::: "memory");
            __builtin_amdgcn_s_barrier();          // all waves' stage-kt landed
            __builtin_amdgcn_sched_barrier(0);
            compute(As[cur], Bs[cur]);
            __builtin_amdgcn_sched_barrier(0);
            __builtin_amdgcn_s_barrier();          // all waves done reading buf cur
            if (kt + 2 < nk) { stageA(cur, kt + 2); stageB(cur, kt + 2); }
            __builtin_amdgcn_sched_barrier(0);
        }
    } else {
        short* bufA = &As[1][0];                 // B buffer for steps kt%4==2
        short* bufB = &As[1][4096];              // B buffer for steps kt%4==3
        #pragma unroll
        for (int i = 0; i < 4; ++i)              // FST tile [64 i][128 row] -> As[0], linear
            GLOAD(Fsrc + i * 2048 + t * 8, &As[0][i * 2048 + t * 8]);
        stageB2(Bs[0], 0); stageB2(Bs[1], 1);    // steps 0,1
        stageB2(bufA, 2);  stageB2(bufB, 3);     // steps 2,3  (12 vm-ops in flight)
        asm volatile("s_waitcnt vmcnt(8)" ::: "memory");   // FST landed
        __builtin_amdgcn_s_barrier();
        __builtin_amdgcn_sched_barrier(0);

        // fj[m][ks][e] = fs[row_m][(ks*4+hi)*8+e] from transposed tile (conflict-free)
        float fj[2][2][8];
        #pragma unroll
        for (int m = 0; m < 2; ++m) {
            int row = w * 32 + m * 16 + lr;
            #pragma unroll
            for (int ks = 0; ks < 2; ++ks) {
                int j0 = (ks * 4 + hi) * 8;
                #pragma unroll
                for (int e = 0; e < 8; ++e)
                    fj[m][ks][e] = bf2f(As[0][(j0 + e) * 128 + row]);
            }
        }

        auto seg2step = [&](const short* bcur, int iidx) {
            float sv[2];
            #pragma unroll
            for (int m = 0; m < 2; ++m)
                sv[m] = bf2f(As[0][iidx * 128 + w * 32 + m * 16 + lr]);
            #pragma unroll
            for (int ks = 0; ks < 2; ++ks) {
                int oct = ((ks * 4 + hi) ^ (lr & 7)) * 8;
                short8v b[4];
                #pragma unroll
                for (int n = 0; n < 4; ++n)
                    b[n] = *(const short8v*)&bcur[(n * 16 + lr) * 64 + oct];
                #pragma unroll
                for (int m = 0; m < 2; ++m) {
                    union { int i32[4]; short8v v; } fa;
                    #pragma unroll
                    for (int q2 = 0; q2 < 4; ++q2)
                        fa.i32[q2] = cvtpk(sv[m] * fj[m][ks][2 * q2], sv[m] * fj[m][ks][2 * q2 + 1]);
                    __builtin_amdgcn_s_setprio(1);
                    #pragma unroll
                    for (int n = 0; n < 4; ++n)
                        acc[m][n] = __builtin_amdgcn_mfma_f32_16x16x32_bf16(fa.v, b[n], acc[m][n], 0, 0, 0);
                    __builtin_amdgcn_s_setprio(0);
                }
            }
        };

        // 8 two-step phases: even p uses Bs[0],Bs[1] (steps 4q,4q+1); odd p uses bufA,bufB.
        for (int p = 0; p < 8; ++p) {
            short* e0 = (p & 1) ? bufA : Bs[0];
            short* e1 = (p & 1) ? bufB : Bs[1];
            if (p < 7) asm volatile("s_waitcnt vmcnt(4)" ::: "memory");
            else       asm volatile("s_waitcnt vmcnt(0)" ::: "memory");
            __builtin_amdgcn_s_barrier();          // all waves' steps 2p,2p+1 landed
            __builtin_amdgcn_sched_barrier(0);
            seg2step(e0, kc * 16 + 2 * p);
            seg2step(e1, kc * 16 + 2 * p + 1);
            __builtin_amdgcn_sched_barrier(0);
            __builtin_amdgcn_s_barrier();          // all waves done with e0,e1
            if (p < 6) { stageB2(e0, 2 * p + 4); stageB2(e1, 2 * p + 5); }
            __builtin_amdgcn_sched_barrier(0);
        }
    }

    int segbase = seg * 256;
    if (seg != 2) {
        #pragma unroll
        for (int m = 0; m < 2; ++m) {
            int row0 = brow + w * 32 + m * 16 + hi * 4;
            #pragma unroll
            for (int n = 0; n < 4; ++n) {
                int col = segbase + bcol + n * 16 + lr;
                #pragma unroll
                for (int r = 0; r < 4; ++r)
                    out[(size_t)(row0 + r) * 768 + col] = acc[m][n][r];
            }
        }
    } else {
        #pragma unroll
        for (int m = 0; m < 2; ++m) {
            int row0 = brow + w * 32 + m * 16 + hi * 4;
            #pragma unroll
            for (int n = 0; n < 4; ++n) {
                int col = segbase + bcol + n * 16 + lr;
                #pragma unroll
                for (int r = 0; r < 4; ++r)
                    unsafeAtomicAdd(&out[(size_t)(row0 + r) * 768 + col], acc[m][n][r]);
            }
        }
    }
}

extern "C" void kernel_launch(void* const* d_in, const int* in_sizes, int n_in,
                              void* d_out, int out_size, void* d_ws, size_t ws_size,
                              hipStream_t stream) {
    const float* embeds = (const float*)d_in[0];
    const float* lw = (const float*)d_in[1];
    const float* iw = (const float*)d_in[2];
    const float* ow = (const float*)d_in[3];
    float* out = (float*)d_out;

    short* A   = (short*)d_ws;                    // 4096*3072*2 = 25,165,824 B
    short* Wt  = A + (size_t)4096 * KA;           // + 256*7168*2 = 3,670,016 B
    short* FST = Wt + (size_t)256 * KW;           // + 32*64*128*2 =   524,288 B

    prep<<<dim3(2304), dim3(256), 0, stream>>>(embeds, lw, iw, ow, A, FST, Wt, (float4*)out);
    gemm_tile<<<dim3(768), dim3(256), 0, stream>>>(A, Wt, FST, out);
}